// Round 2
// baseline (707.723 us; speedup 1.0000x reference)
//
#include <hip/hip_runtime.h>
#include <math.h>

#define BN_EPS 1e-3f

// GEMV split-K geometry: grid = (N/GB_COLS, 2N/GB_ROWS) = (8, 256) = 2048 blocks.
// Each block: 64 rows x 1024 cols partial, written contention-free to ws.
#define GB_ROWS 64
#define GB_COLS 1024

// Native vector type for nontemporal 16B loads (HIP_vector_type is rejected
// by __builtin_nontemporal_load; clang ext_vector_type is accepted).
typedef float floatx4 __attribute__((ext_vector_type(4)));

// Kernel A: one 64-lane wave per node. Lanes gather K=64 neighbor values
// (adj row is a coalesced 256B read; x is 32KB -> L1/L2 resident),
// shuffle-reduce across the wave, lane 0 applies BatchNorm to both halves
// of h = concat([x, x + ngh_sum]) and writes h_bn[2N].
__global__ void agg_bn_kernel(const float* __restrict__ x,
                              const int* __restrict__ adj,
                              const float* __restrict__ bn_gamma,
                              const float* __restrict__ bn_beta,
                              const float* __restrict__ bn_mean,
                              const float* __restrict__ bn_var,
                              float* __restrict__ h_bn,
                              int N, int K)
{
    int gid  = blockIdx.x * blockDim.x + threadIdx.x;
    int node = gid >> 6;
    int lane = gid & 63;
    if (node >= N) return;

    float s = 0.0f;
    for (int k = lane; k < K; k += 64) {
        int nb = adj[(size_t)node * K + k];
        s += x[nb];
    }
#pragma unroll
    for (int off = 32; off > 0; off >>= 1)
        s += __shfl_down(s, off, 64);

    if (lane == 0) {
        float xi  = x[node];
        float agg = xi + s;
        {
            float sc = rsqrtf(bn_var[node] + BN_EPS) * bn_gamma[node];
            h_bn[node] = (xi - bn_mean[node]) * sc + bn_beta[node];
        }
        {
            int j = N + node;
            float sc = rsqrtf(bn_var[j] + BN_EPS) * bn_gamma[j];
            h_bn[j] = (agg - bn_mean[j]) * sc + bn_beta[j];
        }
    }
}

// Kernel B: atomic-free split-K GEMV partial.
// part[by][col0..col0+3] = sum_{r in 64-row chunk} h[r] * W[r][col].
// 2048 blocks -> 8 blocks/CU -> 32 waves/CU (full occupancy).
// W is streamed with nontemporal float4 loads (read-once, keep L2 clean).
__global__ __launch_bounds__(256, 8)
void gemv_partial_kernel(const float* __restrict__ h,
                         const float* __restrict__ W,
                         float* __restrict__ part,
                         int N)
{
    __shared__ float hs[GB_ROWS];
    int row0 = blockIdx.y * GB_ROWS;
    if (threadIdx.x < GB_ROWS)
        hs[threadIdx.x] = h[row0 + threadIdx.x];
    __syncthreads();

    int col = blockIdx.x * GB_COLS + threadIdx.x * 4;
    const float* Wp = W + (size_t)row0 * N + col;

    float ax = 0.0f, ay = 0.0f, az = 0.0f, aw = 0.0f;
#pragma unroll 8
    for (int r = 0; r < GB_ROWS; ++r) {
        floatx4 w = __builtin_nontemporal_load(
            reinterpret_cast<const floatx4*>(Wp));
        float hv = hs[r];
        ax = fmaf(hv, w.x, ax);
        ay = fmaf(hv, w.y, ay);
        az = fmaf(hv, w.z, az);
        aw = fmaf(hv, w.w, aw);
        Wp += N;
    }
    floatx4 o = { ax, ay, az, aw };
    *reinterpret_cast<floatx4*>(part + (size_t)blockIdx.y * N + col) = o;
}

// Kernel C: reduce the RY=2N/GB_ROWS partials per column, add bias, exact-erf gelu.
// Block = 256 threads covering 64 columns x 4 reduction slices; lanes of a wave
// read 64 consecutive columns (256B coalesced per wave-load).
__global__ __launch_bounds__(256)
void reduce_bias_gelu_kernel(const float* __restrict__ part,
                             const float* __restrict__ b,
                             float* __restrict__ out,
                             int N, int RY)
{
    __shared__ float sm[4][64];
    int lane = threadIdx.x & 63;
    int wv   = threadIdx.x >> 6;
    int col  = blockIdx.x * 64 + lane;

    float s = 0.0f;
    for (int ry = wv; ry < RY; ry += 4)
        s += part[(size_t)ry * N + col];
    sm[wv][lane] = s;
    __syncthreads();

    if (threadIdx.x < 64) {
        float v = sm[0][lane] + sm[1][lane] + sm[2][lane] + sm[3][lane] + b[col];
        out[col] = 0.5f * v * (1.0f + erff(v * 0.70710678118654752f));
    }
}

extern "C" void kernel_launch(void* const* d_in, const int* in_sizes, int n_in,
                              void* d_out, int out_size, void* d_ws, size_t ws_size,
                              hipStream_t stream)
{
    const float* x   = (const float*)d_in[0];   // [1, N]
    const int*   adj = (const int*)d_in[1];     // [N, K] (integer -> int32 per harness)
    // d_in[2] = edge_weights: unused by the reference
    const float* W   = (const float*)d_in[3];   // [2N, N]
    const float* b   = (const float*)d_in[4];   // [N]
    const float* g   = (const float*)d_in[5];   // bn_gamma [2N]
    const float* be  = (const float*)d_in[6];   // bn_beta  [2N]
    const float* mn  = (const float*)d_in[7];   // bn_mean  [2N]
    const float* vr  = (const float*)d_in[8];   // bn_var   [2N]
    float* out = (float*)d_out;

    int N = in_sizes[0];       // 8192
    int K = in_sizes[1] / N;   // 64
    int RY = (2 * N) / GB_ROWS; // 256 partial slices

    // Workspace layout: part [RY * N] floats (8 MiB) | h_bn [2N] floats.
    // Every partial element is fully written by kernel B before kernel C reads
    // it, so no zero-init (and no memset dispatch) is needed.
    float* part = (float*)d_ws;
    float* h_bn = part + (size_t)RY * N;

    {
        // one 64-lane wave per node
        long long total_threads = (long long)N * 64;
        int threads = 256;
        int blocks = (int)((total_threads + threads - 1) / threads);
        agg_bn_kernel<<<blocks, threads, 0, stream>>>(x, adj, g, be, mn, vr, h_bn, N, K);
    }
    {
        dim3 grid(N / GB_COLS, RY);   // (8, 256) = 2048 blocks
        gemv_partial_kernel<<<grid, 256, 0, stream>>>(h_bn, W, part, N);
    }
    reduce_bias_gelu_kernel<<<N / 64, 256, 0, stream>>>(part, b, out, N, RY);
}